// Round 2
// baseline (420.478 us; speedup 1.0000x reference)
//
#include <hip/hip_runtime.h>
#include <hip/hip_cooperative_groups.h>
#include <stdint.h>

namespace cg = cooperative_groups;

#define B_      4
#define S_      8
#define C_      1024
#define DK_     1024
#define MAXLEN_ 8192
#define SIZE_   4096   // token_ind + 1
#define NCH     64     // chunks per batch
#define CHR     64     // rows per chunk
#define NTOK    (SIZE_ - 1)   // 4095: the row k_new/v_new occupy (never written to caches)

typedef unsigned short ushort_t;
typedef unsigned int   uint_t;
typedef float f32x4 __attribute__((ext_vector_type(4)));

__device__ __forceinline__ float bf2f(ushort_t u) {
    union { uint_t u; float f; } v; v.u = ((uint_t)u) << 16; return v.f;
}
__device__ __forceinline__ ushort_t f2bf(float f) {
    union { float f; uint_t u; } v; v.f = f;
    uint_t u = v.u;
    uint_t lsb = (u >> 16) & 1u;
    u += 0x7fffu + lsb;          // round-to-nearest-even
    return (ushort_t)(u >> 16);
}

// ---------------------------------------------------------------------------
// K1: split-K qkv partial GEMM.  grid (24, 8):
//   blockIdx.x = col-tile (128 cols of 3072), blockIdx.y = row-tile (128 rows of 1024)
// part[rowtile][b*3072 + col] = sum_{r in tile} x[b][7][r] * W[r][col]
// W is read ONCE (all 4 batches share the load), float4 vectorized, 192 blocks.
// ---------------------------------------------------------------------------
__global__ void __launch_bounds__(256) k_qkv_partial(
        const float* __restrict__ x, const float* __restrict__ W,
        float* __restrict__ part) {
    __shared__ float xs[B_][128];
    __shared__ float red[8][32][16];   // [rowgroup][colgroup][b*4+cc]  (16 KB)
    int t  = threadIdx.x;
    int cg_ = t & 31;       // 32 col-groups of 4 cols
    int rg  = t >> 5;       // 8 row-groups of 16 rows
    int c0 = blockIdx.x * 128;
    int r0 = blockIdx.y * 128;

    for (int i = t; i < B_ * 128; i += 256) {
        int b = i >> 7, r = i & 127;
        xs[b][r] = x[((b * S_) + (S_ - 1)) * C_ + r0 + r];
    }
    __syncthreads();

    float acc[B_][4] = {};
    const float* wp = W + (size_t)(r0 + rg * 16) * (3 * DK_) + c0 + cg_ * 4;
#pragma unroll 8
    for (int i = 0; i < 16; ++i) {
        f32x4 wv = *(const f32x4*)(wp + (size_t)i * (3 * DK_));
        int r = rg * 16 + i;
#pragma unroll
        for (int b = 0; b < B_; ++b) {
            float xv = xs[b][r];
            acc[b][0] += xv * wv[0];
            acc[b][1] += xv * wv[1];
            acc[b][2] += xv * wv[2];
            acc[b][3] += xv * wv[3];
        }
    }
#pragma unroll
    for (int b = 0; b < B_; ++b)
#pragma unroll
        for (int cc = 0; cc < 4; ++cc)
            red[rg][cg_][b * 4 + cc] = acc[b][cc];
    __syncthreads();

    if (t < 32) {
#pragma unroll
        for (int b = 0; b < B_; ++b) {
            float s0 = 0.f, s1 = 0.f, s2 = 0.f, s3 = 0.f;
#pragma unroll
            for (int r = 0; r < 8; ++r) {
                s0 += red[r][t][b * 4 + 0];
                s1 += red[r][t][b * 4 + 1];
                s2 += red[r][t][b * 4 + 2];
                s3 += red[r][t][b * 4 + 3];
            }
            f32x4 v = { s0, s1, s2, s3 };
            *(f32x4*)(part + (size_t)blockIdx.y * (B_ * 3 * DK_) + b * (3 * DK_) + c0 + t * 4) = v;
        }
    }
}

// ---------------------------------------------------------------------------
// K2: cooperative mega-kernel. grid = 256 blocks (b = bid>>6, c = bid&63), 256 thr.
// ph0: finish qkv (sum 8 partials + bias) -> q/k/v in ws        (blocks 0..47)
// ph1: scores for chunk rows (q·k/32, shfl reduce) -> LDS; chunk max -> pmax
// ph2: global max M, e=exp(s-M) -> LDS es; csum -> ws; chunk V-sum -> P (bf16)
// ph3: register-resident exclusive scan of P over chunks (16 blocks);
//      shfl exclusive scan of csum -> Epre (4 blocks)
// ph4: walk chunk rows: acc += e*V, S += e, out = acc/S (nontemporal stores)
// Caches are NEVER written; row 4095 K/V come from ws.
// ---------------------------------------------------------------------------
__global__ void __launch_bounds__(256) k_coop(
        const float* __restrict__ kc, const float* __restrict__ vc,
        const float* __restrict__ bias, const float* __restrict__ part,
        float* __restrict__ qkvws, float* __restrict__ pmax,
        float* __restrict__ csum, float* __restrict__ Epre,
        ushort_t* __restrict__ P, float* __restrict__ out) {
    cg::grid_group grid = cg::this_grid();
    __shared__ float s_lds[NCH];
    __shared__ float es[CHR];
    __shared__ float redm[1];
    int t    = threadIdx.x;
    int bid  = blockIdx.x;
    int b    = bid >> 6;
    int c    = bid & 63;
    int lane = t & 63;
    int wv   = t >> 6;

    // ---- ph0: finish qkv ----
    if (bid < 48) {
        int i   = bid * 256 + t;          // flat (b,col) over 4*3072
        int bq  = i / 3072;
        int col = i - bq * 3072;
        float s = bias[col];
#pragma unroll
        for (int rt = 0; rt < 8; ++rt) s += part[rt * (B_ * 3 * DK_) + i];
        qkvws[(col >> 10) * (B_ * DK_) + bq * DK_ + (col & (DK_ - 1))] = s;
    }
    grid.sync();

    // ---- ph1: scores + chunk max ----
    {
        const float* qp = qkvws + b * DK_ + lane * 4;
        f32x4 q0 = *(const f32x4*)(qp);
        f32x4 q1 = *(const f32x4*)(qp + 256);
        f32x4 q2 = *(const f32x4*)(qp + 512);
        f32x4 q3 = *(const f32x4*)(qp + 768);
        int j0 = c * CHR + wv * 16;
#pragma unroll 2
        for (int r = 0; r < 16; ++r) {
            int j = j0 + r;
            const float* kp = (j == NTOK)
                ? (qkvws + (B_ * DK_) + b * DK_)
                : (kc + ((size_t)b * MAXLEN_ + j) * DK_);
            kp += lane * 4;
            f32x4 k0 = *(const f32x4*)(kp);
            f32x4 k1 = *(const f32x4*)(kp + 256);
            f32x4 k2 = *(const f32x4*)(kp + 512);
            f32x4 k3 = *(const f32x4*)(kp + 768);
            float acc = k0[0]*q0[0] + k0[1]*q0[1] + k0[2]*q0[2] + k0[3]*q0[3]
                      + k1[0]*q1[0] + k1[1]*q1[1] + k1[2]*q1[2] + k1[3]*q1[3]
                      + k2[0]*q2[0] + k2[1]*q2[1] + k2[2]*q2[2] + k2[3]*q2[3]
                      + k3[0]*q3[0] + k3[1]*q3[1] + k3[2]*q3[2] + k3[3]*q3[3];
#pragma unroll
            for (int off = 32; off > 0; off >>= 1) acc += __shfl_down(acc, off, 64);
            if (lane == 0) s_lds[wv * 16 + r] = acc * 0.03125f;
        }
        __syncthreads();
        if (t < 64) {
            float mv = s_lds[t];
#pragma unroll
            for (int off = 32; off > 0; off >>= 1) mv = fmaxf(mv, __shfl_down(mv, off, 64));
            if (t == 0) pmax[bid] = mv;
        }
    }
    grid.sync();

    // ---- ph2: M, e, csum, chunk V-sum -> P ----
    {
        if (t < 64) {
            float mv = pmax[b * 64 + t];
#pragma unroll
            for (int off = 32; off > 0; off >>= 1) mv = fmaxf(mv, __shfl_down(mv, off, 64));
            if (t == 0) redm[0] = mv;
        }
        __syncthreads();
        float M = redm[0];
        if (t < 64) {
            float e = __expf(s_lds[t] - M);
            es[t] = e;
#pragma unroll
            for (int off = 32; off > 0; off >>= 1) e += __shfl_down(e, off, 64);
            if (t == 0) csum[bid] = e;
        }
        __syncthreads();

        int d0 = t * 4;
        const float* vbase = vc + ((size_t)b * MAXLEN_ + c * CHR) * DK_ + d0;
        float a0 = 0.f, a1 = 0.f, a2 = 0.f, a3 = 0.f;
#pragma unroll 4
        for (int r = 0; r < CHR - 1; ++r) {
            f32x4 u = *(const f32x4*)(vbase + (size_t)r * DK_);
            float ee = es[r];
            a0 += ee * u[0]; a1 += ee * u[1]; a2 += ee * u[2]; a3 += ee * u[3];
        }
        {
            const float* v63 = (c == NCH - 1)
                ? (qkvws + 2 * (B_ * DK_) + b * DK_ + d0)
                : (vbase + (size_t)(CHR - 1) * DK_);
            f32x4 u = *(const f32x4*)(v63);
            float ee = es[CHR - 1];
            a0 += ee * u[0]; a1 += ee * u[1]; a2 += ee * u[2]; a3 += ee * u[3];
        }
        ushort4 pv;
        pv.x = f2bf(a0); pv.y = f2bf(a1); pv.z = f2bf(a2); pv.w = f2bf(a3);
        *(ushort4*)(P + (size_t)bid * DK_ + d0) = pv;
    }
    grid.sync();

    // ---- ph3: scans ----
    if (bid < 16) {
        // register-resident exclusive scan of P along chunk axis
        int bs = bid >> 2, dg = bid & 3;
        ushort_t* Pd = P + (size_t)bs * NCH * DK_ + dg * 256 + t;
        ushort_t vals[NCH];
#pragma unroll
        for (int cc = 0; cc < NCH; ++cc) vals[cc] = Pd[cc * DK_];   // 64 independent loads
        float run = 0.f;
#pragma unroll
        for (int cc = 0; cc < NCH; ++cc) {
            float tmp = bf2f(vals[cc]);
            Pd[cc * DK_] = f2bf(run);
            run += tmp;
        }
    } else if (bid < 20) {
        // exclusive scan of csum -> Epre via wave shuffles
        int bs = bid - 16;
        if (t < 64) {
            float v = csum[bs * 64 + t];
            float sc = v;
#pragma unroll
            for (int off = 1; off < 64; off <<= 1) {
                float o = __shfl_up(sc, off, 64);
                if (t >= off) sc += o;
            }
            Epre[bs * 64 + t] = sc - v;
        }
    }
    grid.sync();

    // ---- ph4: output walk ----
    {
        int d0 = t * 4;
        ushort4 pv = *(const ushort4*)(P + (size_t)bid * DK_ + d0);
        float a0 = bf2f(pv.x), a1 = bf2f(pv.y), a2 = bf2f(pv.z), a3 = bf2f(pv.w);
        float S = Epre[bid];
        const float* vbase = vc + ((size_t)b * MAXLEN_ + c * CHR) * DK_ + d0;
        float* obase = out + ((size_t)b * SIZE_ + c * CHR) * DK_ + d0;
#pragma unroll 4
        for (int r = 0; r < CHR - 1; ++r) {
            f32x4 u = *(const f32x4*)(vbase + (size_t)r * DK_);
            float ee = es[r];
            a0 += ee * u[0]; a1 += ee * u[1]; a2 += ee * u[2]; a3 += ee * u[3];
            S += ee;
            float inv = 1.0f / S;
            f32x4 ov = { a0 * inv, a1 * inv, a2 * inv, a3 * inv };
            __builtin_nontemporal_store(ov, (f32x4*)(obase + (size_t)r * DK_));
        }
        {
            const float* v63 = (c == NCH - 1)
                ? (qkvws + 2 * (B_ * DK_) + b * DK_ + d0)
                : (vbase + (size_t)(CHR - 1) * DK_);
            f32x4 u = *(const f32x4*)(v63);
            float ee = es[CHR - 1];
            a0 += ee * u[0]; a1 += ee * u[1]; a2 += ee * u[2]; a3 += ee * u[3];
            S += ee;
            float inv = 1.0f / S;
            f32x4 ov = { a0 * inv, a1 * inv, a2 * inv, a3 * inv };
            __builtin_nontemporal_store(ov, (f32x4*)(obase + (size_t)(CHR - 1) * DK_));
        }
    }
}

extern "C" void kernel_launch(void* const* d_in, const int* in_sizes, int n_in,
                              void* d_out, int out_size, void* d_ws, size_t ws_size,
                              hipStream_t stream) {
    (void)in_sizes; (void)n_in; (void)out_size; (void)ws_size;
    const float* x    = (const float*)d_in[0];
    const float* W    = (const float*)d_in[1];
    const float* bias = (const float*)d_in[2];
    const float* kc   = (const float*)d_in[3];   // read-only
    const float* vc   = (const float*)d_in[4];   // read-only
    float* out        = (float*)d_out;

    // ws layout (float offsets), total 144128 floats = 576 KB:
    //   P     @ 0       : [4][64][1024] bf16 = 262144 ushorts = 131072 floats (512 KB)
    //   part  @ 0       : [8][12288] fp32 split-K partials (384 KB) -- aliases P's
    //                     front; part is dead after ph0, P first written in ph2.
    //   qkvws @ 131072  : q[4][1024] | k_new[4][1024] | v_new[4][1024] (48 KB)
    //   pmax  @ 143360  : [4][64]
    //   csum  @ 143616  : [4][64]
    //   Epre  @ 143872  : [4][64]
    float* ws    = (float*)d_ws;
    float* part  = ws;
    float* qkvws = ws + 131072;
    float* pmax  = ws + 143360;
    float* csum  = ws + 143616;
    float* Epre  = ws + 143872;
    ushort_t* P  = (ushort_t*)ws;

    hipLaunchKernelGGL(k_qkv_partial, dim3(24, 8), dim3(256), 0, stream, x, W, part);

    void* args[] = { (void*)&kc, (void*)&vc, (void*)&bias, (void*)&part, (void*)&qkvws,
                     (void*)&pmax, (void*)&csum, (void*)&Epre, (void*)&P, (void*)&out };
    hipLaunchCooperativeKernel((const void*)k_coop, dim3(256), dim3(256), args, 0, stream);
}